// Round 9
// baseline (460.027 us; speedup 1.0000x reference)
//
#include <hip/hip_runtime.h>
#include <math.h>

#define DIM 128
#define NRES 262144

typedef __attribute__((ext_vector_type(8))) short short8;
typedef __attribute__((ext_vector_type(4))) float f32x4;

__device__ __forceinline__ float sigmoidf_(float x) {
    return 1.0f / (1.0f + __expf(-x));
}
__device__ __forceinline__ float tanhf_(float x) {
    return 1.0f - 2.0f / (__expf(2.0f * x) + 1.0f);
}
__device__ __forceinline__ unsigned short f2bf(float f) {
    unsigned int u = __float_as_uint(f);
    unsigned int r = u + 0x7FFFu + ((u >> 16) & 1u);
    return (unsigned short)(r >> 16);
}
__device__ __forceinline__ float bf2f(unsigned short s) {
    return __uint_as_float(((unsigned int)s) << 16);
}

// W f32 [640][256] -> bf16 [640][256]
__global__ void convert_w_kernel(const float* __restrict__ W, unsigned short* __restrict__ Wb) {
    int i = blockIdx.x * 256 + threadIdx.x;
    float4 v = ((const float4*)W)[i];
    unsigned short o[4] = {f2bf(v.x), f2bf(v.y), f2bf(v.z), f2bf(v.w)};
    *(ushort4*)(Wb + i * 4) = *(ushort4*)o;
}

// ---- 4-level fused tree-LSTM pass ----
// Block: 64 input h-rows = 32 A-rows of 256 -> 4 levels in LDS -> 4 output rows.
// 512 thr = 8 waves; wave w owns d-slice [16w,16w+16) for all 5 gates; W resident
// in 160 VGPRs (VOLATILE loads = exactly-once; __launch_bounds__(512,1) -> 2
// waves/SIMD -> 256-VGPR cap so Breg+acc fits WITHOUT spill. (512,2) capped at
// 128 and spilled Breg to scratch - the round-8 failure.) h in LDS: row-major
// 256-ushort A-rows, 16B chunks XOR-swizzled (chunk ^ (row&7)); c in LDS as f32,
// stride 132. LEAF pass fuses the leaves-output write-through (coalesced).
// LDS map (bytes): H0 [0,16384) | H1 [16384,24576) | C0 [24576,41472) s132 |
//   C1 [41472,49920) | ROOTS [49920,51968)
template<bool LEAF, bool LASTPASS>
__global__ __launch_bounds__(512, 1)
void fused4_kernel(const void* __restrict__ x_in,
                   const float* __restrict__ c_in,
                   const unsigned short* __restrict__ Wb,
                   const float* __restrict__ bvec,
                   unsigned short* __restrict__ h_out,
                   float* __restrict__ c_out,
                   float* __restrict__ out) {
    __shared__ __align__(16) unsigned char lds[51968];
    unsigned short* H0 = (unsigned short*)lds;
    unsigned short* H1 = (unsigned short*)(lds + 16384);
    float* C0 = (float*)(lds + 24576);
    float* C1 = (float*)(lds + 41472);
    float* ROOTS = (float*)(lds + 49920);

    const int t = threadIdx.x;
    const int lane = t & 63;
    const int wid = t >> 6;
    const int col = lane & 15;
    const int kg = lane >> 4;
    const int d = wid * 16 + col;

    // ---- W resident: 5 gates x 8 k-chunks x short8 = 160 VGPR.
    short8 Breg[5][8];
    {
        const unsigned short* wbase = Wb + (size_t)d * 256 + kg * 8;
        #pragma unroll
        for (int g = 0; g < 5; ++g)
            #pragma unroll
            for (int kc = 0; kc < 8; ++kc)
                Breg[g][kc] = *(const volatile short8*)(wbase + (size_t)g * 32768 + kc * 32);
    }
    float bias[5];
    #pragma unroll
    for (int g = 0; g < 5; ++g) bias[g] = bvec[g * 128 + d];

    // ---- stage 32 A-rows into H0 (row-major, chunk-XOR swizzle)
    if (LEAF) {
        const float* xf = (const float*)x_in + (size_t)blockIdx.x * 8192;   // 64 leaf rows
        float* outw = out + 256 + (size_t)blockIdx.x * 16384;               // 64 out rows
        #pragma unroll
        for (int i = 0; i < 2; ++i) {
            int j = i * 512 + t;       // chunk 0..1023
            int r = j >> 5, c = j & 31;
            const float* s = xf + r * 256 + c * 8;
            float4 u0 = *(const float4*)s;
            float4 u1 = *(const float4*)(s + 4);
            unsigned short o[8] = {f2bf(u0.x), f2bf(u0.y), f2bf(u0.z), f2bf(u0.w),
                                   f2bf(u1.x), f2bf(u1.y), f2bf(u1.z), f2bf(u1.w)};
            *(short8*)&H0[r * 256 + ((c ^ (r & 7)) * 8)] = *(short8*)o;
            // fused leaves write-through (coalesced: lanes cover contiguous 32B)
            int l = 2 * r + (c >> 4);
            float* wdst = outw + (size_t)l * 256 + (c & 15) * 8;
            float4 z4 = make_float4(0.f, 0.f, 0.f, 0.f);
            *(float4*)wdst = u0;
            *(float4*)(wdst + 4) = u1;
            *(float4*)(wdst + 128) = z4;
            *(float4*)(wdst + 132) = z4;
        }
    } else {
        const unsigned short* xb = (const unsigned short*)x_in + (size_t)blockIdx.x * 8192;
        #pragma unroll
        for (int i = 0; i < 2; ++i) {
            int j0 = i * 512 + wid * 64;   // wave-uniform chunk base
            int j = j0 + lane;
            int r = j >> 5, c = j & 31;
            __builtin_amdgcn_global_load_lds(
                (const __attribute__((address_space(1))) unsigned int*)(xb + (size_t)r * 256 + ((c ^ (r & 7)) * 8)),
                (__attribute__((address_space(3))) unsigned int*)&H0[j0 * 8],
                16, 0, 0);
        }
    }
    __syncthreads();

#define EPI(ACC, MF) do {                                                              \
    _Pragma("unroll")                                                                  \
    for (int r4 = 0; r4 < 4; ++r4) {                                                   \
        const int P = (MF) * 16 + kg * 4 + r4;                                         \
        if (P < parents) {                                                             \
            float iv = sigmoidf_(ACC[0][r4] + bias[0]);                                \
            float fl = sigmoidf_(ACC[1][r4] + bias[1]);                                \
            float fr = sigmoidf_(ACC[2][r4] + bias[2]);                                \
            float ov = sigmoidf_(ACC[3][r4] + bias[3]);                                \
            float gv = tanhf_(ACC[4][r4] + bias[4]);                                   \
            float cl = 0.f, cr = 0.f;                                                  \
            if (lvl == 0) {                                                            \
                if (!LEAF) {                                                           \
                    size_t cb = ((size_t)blockIdx.x * 64 + 2 * P) * 128 + d;           \
                    cl = c_in[cb]; cr = c_in[cb + 128];                                \
                }                                                                      \
            } else {                                                                   \
                cl = csrc[(2 * P) * 132 + d];                                          \
                cr = csrc[(2 * P + 1) * 132 + d];                                      \
            }                                                                          \
            float cn = fl * cl + fr * cr + iv * gv;                                    \
            float hn = ov * tanhf_(cn);                                                \
            if (last) {                                                                \
                if (LASTPASS) {                                                        \
                    ROOTS[P * 128 + d] = hn;                                           \
                } else {                                                               \
                    size_t oo = ((size_t)blockIdx.x * 4 + P) * 128 + d;                \
                    h_out[oo] = f2bf(hn);                                              \
                    c_out[oo] = cn;                                                    \
                }                                                                      \
            } else {                                                                   \
                int rw = P >> 1;                                                       \
                int c2 = ((P & 1) * 16 + (d >> 3)) ^ (rw & 7);                         \
                hd[rw * 256 + c2 * 8 + (d & 7)] = f2bf(hn);                            \
                cdst[P * 132 + d] = cn;                                                \
            }                                                                          \
        }                                                                              \
    }                                                                                  \
} while (0)

    unsigned short* hs = H0;
    unsigned short* hd = H1;
    float* csrc = C1;   // unused at lvl 0
    float* cdst = C0;
    int parents = 32;

    #pragma unroll
    for (int lvl = 0; lvl < 4; ++lvl) {
        const bool last = (lvl == 3);
        const bool hiv = (parents > 16);
        f32x4 acc0[5], acc1[5];
        #pragma unroll
        for (int g = 0; g < 5; ++g) {
            acc0[g] = (f32x4){0.f, 0.f, 0.f, 0.f};
            acc1[g] = (f32x4){0.f, 0.f, 0.f, 0.f};
        }
        #pragma unroll
        for (int kc = 0; kc < 8; ++kc) {
            int q = (kc * 4 + kg) ^ (col & 7);
            short8 a0 = *(const short8*)&hs[col * 256 + q * 8];
            #pragma unroll
            for (int g = 0; g < 5; ++g)
                acc0[g] = __builtin_amdgcn_mfma_f32_16x16x32_bf16(a0, Breg[g][kc], acc0[g], 0, 0, 0);
            if (hiv) {
                short8 a1 = *(const short8*)&hs[(16 + col) * 256 + q * 8];
                #pragma unroll
                for (int g = 0; g < 5; ++g)
                    acc1[g] = __builtin_amdgcn_mfma_f32_16x16x32_bf16(a1, Breg[g][kc], acc1[g], 0, 0, 0);
            }
        }
        EPI(acc0, 0);
        if (hiv) EPI(acc1, 1);
        __syncthreads();
        { unsigned short* th = hs; hs = hd; hd = th; }
        { float* tc = csrc; csrc = cdst; cdst = tc; }
        parents >>= 1;
    }
#undef EPI

    if (LASTPASS) {
        if (t < 128) {
            out[t] = 0.25f * (ROOTS[t] + ROOTS[128 + t] + ROOTS[256 + t] + ROOTS[384 + t]);
        } else if (t < 256) {
            out[t] = 0.0f;
        }
    }
}

extern "C" void kernel_launch(void* const* d_in, const int* in_sizes, int n_in,
                              void* d_out, int out_size, void* d_ws, size_t ws_size,
                              hipStream_t stream) {
    const float* leaf = (const float*)d_in[0];
    const float* W_up = (const float*)d_in[1];
    const float* b_up = (const float*)d_in[2];
    float* out = (float*)d_out;
    char* ws = (char*)d_ws;

    unsigned short* Wb = (unsigned short*)ws;                  // 320 KB
    unsigned short* h1 = (unsigned short*)(ws + 0x100000);     // 16384x128 bf16 = 4 MB
    float* c1 = (float*)(ws + 0x500000);                       // 16384x128 f32 = 8 MB
    unsigned short* h2 = (unsigned short*)(ws + 0xD00000);     // 1024x128 bf16 = 256 KB
    float* c2 = (float*)(ws + 0xD40000);                       // 512 KB
    unsigned short* h3 = (unsigned short*)(ws + 0xDC0000);     // 64x128 bf16 = 16 KB
    float* c3 = (float*)(ws + 0xDC8000);                       // 32 KB

    convert_w_kernel<<<160, 256, 0, stream>>>(W_up, Wb);

    // P1: 262144 leaves -> 16384 rows (levels 1-4) + leaves write-through
    fused4_kernel<true, false><<<4096, 512, 0, stream>>>(leaf, nullptr, Wb, b_up, h1, c1, out);
    // P2: 16384 -> 1024 (levels 5-8)
    fused4_kernel<false, false><<<256, 512, 0, stream>>>(h1, c1, Wb, b_up, h2, c2, nullptr);
    // P3: 1024 -> 64 (levels 9-12)
    fused4_kernel<false, false><<<16, 512, 0, stream>>>(h2, c2, Wb, b_up, h3, c3, nullptr);
    // P4: 64 -> 4 roots (levels 13-16) + mean + out[128:256]=0
    fused4_kernel<false, true><<<1, 512, 0, stream>>>(h3, c3, Wb, b_up, nullptr, nullptr, out);
}

// Round 10
// 439.219 us; speedup vs baseline: 1.0474x; 1.0474x over previous
//
#include <hip/hip_runtime.h>
#include <math.h>

#define DIM 128
#define NRES 262144

typedef __attribute__((ext_vector_type(8))) short short8;
typedef __attribute__((ext_vector_type(4))) float f32x4;

__device__ __forceinline__ float sigmoidf_(float x) {
    return 1.0f / (1.0f + __expf(-x));
}
__device__ __forceinline__ float tanhf_(float x) {
    return 1.0f - 2.0f / (__expf(2.0f * x) + 1.0f);
}
__device__ __forceinline__ unsigned short f2bf(float f) {
    unsigned int u = __float_as_uint(f);
    unsigned int r = u + 0x7FFFu + ((u >> 16) & 1u);
    return (unsigned short)(r >> 16);
}
__device__ __forceinline__ float bf2f(unsigned short s) {
    return __uint_as_float(((unsigned int)s) << 16);
}

// W f32 [640][256] -> bf16 [640][256]
__global__ void convert_w_kernel(const float* __restrict__ W, unsigned short* __restrict__ Wb) {
    int i = blockIdx.x * 256 + threadIdx.x;
    float4 v = ((const float4*)W)[i];
    unsigned short o[4] = {f2bf(v.x), f2bf(v.y), f2bf(v.z), f2bf(v.w)};
    *(ushort4*)(Wb + i * 4) = *(ushort4*)o;
}

// ---- 4-level fused tree-LSTM pass ----
// Block: 64 input h-rows = 32 A-rows of 256 -> 4 levels in LDS -> 4 output rows.
// 512 thr = 8 waves; wave w owns d-slice [16w,16w+16) for all 5 gates; W resident
// in 160 VGPRs. REGISTER BUDGET: amdgpu_waves_per_eu(2,2) pins the allocator to
// exactly 2 waves/EU -> 256-VGPR budget (Breg 160 + acc 40 + temps ~35 fits).
// Rounds 7-9 failed because launch_bounds variants let the occupancy heuristic
// choose 128 regs and spill Breg to scratch. h in LDS: row-major 256-ushort
// A-rows, 16B chunks XOR-swizzled (chunk ^ (row&7)); c in LDS as f32 stride 132.
// LEAF pass fuses the leaves-output write-through (coalesced).
// LDS map (bytes): H0 [0,16384) | H1 [16384,24576) | C0 [24576,41472) s132 |
//   C1 [41472,49920) | ROOTS [49920,51968)
template<bool LEAF, bool LASTPASS>
__global__ __attribute__((amdgpu_flat_work_group_size(512, 512), amdgpu_waves_per_eu(2, 2)))
void fused4_kernel(const void* __restrict__ x_in,
                   const float* __restrict__ c_in,
                   const unsigned short* __restrict__ Wb,
                   const float* __restrict__ bvec,
                   unsigned short* __restrict__ h_out,
                   float* __restrict__ c_out,
                   float* __restrict__ out) {
    __shared__ __align__(16) unsigned char lds[51968];
    unsigned short* H0 = (unsigned short*)lds;
    unsigned short* H1 = (unsigned short*)(lds + 16384);
    float* C0 = (float*)(lds + 24576);
    float* C1 = (float*)(lds + 41472);
    float* ROOTS = (float*)(lds + 49920);

    const int t = threadIdx.x;
    const int lane = t & 63;
    const int wid = t >> 6;
    const int col = lane & 15;
    const int kg = lane >> 4;
    const int d = wid * 16 + col;

    // ---- W resident: 5 gates x 8 k-chunks x short8 = 160 VGPR.
    short8 Breg[5][8];
    {
        const unsigned short* wbase = Wb + (size_t)d * 256 + kg * 8;
        #pragma unroll
        for (int g = 0; g < 5; ++g)
            #pragma unroll
            for (int kc = 0; kc < 8; ++kc)
                Breg[g][kc] = *(const short8*)(wbase + (size_t)g * 32768 + kc * 32);
    }
    float bias[5];
    #pragma unroll
    for (int g = 0; g < 5; ++g) bias[g] = bvec[g * 128 + d];

    // ---- stage 32 A-rows into H0 (row-major, chunk-XOR swizzle)
    if (LEAF) {
        const float* xf = (const float*)x_in + (size_t)blockIdx.x * 8192;   // 64 leaf rows
        float* outw = out + 256 + (size_t)blockIdx.x * 16384;               // 64 out rows
        #pragma unroll
        for (int i = 0; i < 2; ++i) {
            int j = i * 512 + t;       // chunk 0..1023
            int r = j >> 5, c = j & 31;
            const float* s = xf + r * 256 + c * 8;
            float4 u0 = *(const float4*)s;
            float4 u1 = *(const float4*)(s + 4);
            unsigned short o[8] = {f2bf(u0.x), f2bf(u0.y), f2bf(u0.z), f2bf(u0.w),
                                   f2bf(u1.x), f2bf(u1.y), f2bf(u1.z), f2bf(u1.w)};
            *(short8*)&H0[r * 256 + ((c ^ (r & 7)) * 8)] = *(short8*)o;
            // fused leaves write-through (coalesced: lanes cover contiguous 32B)
            int l = 2 * r + (c >> 4);
            float* wdst = outw + (size_t)l * 256 + (c & 15) * 8;
            float4 z4 = make_float4(0.f, 0.f, 0.f, 0.f);
            *(float4*)wdst = u0;
            *(float4*)(wdst + 4) = u1;
            *(float4*)(wdst + 128) = z4;
            *(float4*)(wdst + 132) = z4;
        }
    } else {
        const unsigned short* xb = (const unsigned short*)x_in + (size_t)blockIdx.x * 8192;
        #pragma unroll
        for (int i = 0; i < 2; ++i) {
            int j0 = i * 512 + wid * 64;   // wave-uniform chunk base
            int j = j0 + lane;
            int r = j >> 5, c = j & 31;
            __builtin_amdgcn_global_load_lds(
                (const __attribute__((address_space(1))) unsigned int*)(xb + (size_t)r * 256 + ((c ^ (r & 7)) * 8)),
                (__attribute__((address_space(3))) unsigned int*)&H0[j0 * 8],
                16, 0, 0);
        }
    }
    __syncthreads();

#define EPI(ACC, MF) do {                                                              \
    _Pragma("unroll")                                                                  \
    for (int r4 = 0; r4 < 4; ++r4) {                                                   \
        const int P = (MF) * 16 + kg * 4 + r4;                                         \
        if (P < parents) {                                                             \
            float iv = sigmoidf_(ACC[0][r4] + bias[0]);                                \
            float fl = sigmoidf_(ACC[1][r4] + bias[1]);                                \
            float fr = sigmoidf_(ACC[2][r4] + bias[2]);                                \
            float ov = sigmoidf_(ACC[3][r4] + bias[3]);                                \
            float gv = tanhf_(ACC[4][r4] + bias[4]);                                   \
            float cl = 0.f, cr = 0.f;                                                  \
            if (lvl == 0) {                                                            \
                if (!LEAF) {                                                           \
                    size_t cb = ((size_t)blockIdx.x * 64 + 2 * P) * 128 + d;           \
                    cl = c_in[cb]; cr = c_in[cb + 128];                                \
                }                                                                      \
            } else {                                                                   \
                cl = csrc[(2 * P) * 132 + d];                                          \
                cr = csrc[(2 * P + 1) * 132 + d];                                      \
            }                                                                          \
            float cn = fl * cl + fr * cr + iv * gv;                                    \
            float hn = ov * tanhf_(cn);                                                \
            if (last) {                                                                \
                if (LASTPASS) {                                                        \
                    ROOTS[P * 128 + d] = hn;                                           \
                } else {                                                               \
                    size_t oo = ((size_t)blockIdx.x * 4 + P) * 128 + d;                \
                    h_out[oo] = f2bf(hn);                                              \
                    c_out[oo] = cn;                                                    \
                }                                                                      \
            } else {                                                                   \
                int rw = P >> 1;                                                       \
                int c2 = ((P & 1) * 16 + (d >> 3)) ^ (rw & 7);                         \
                hd[rw * 256 + c2 * 8 + (d & 7)] = f2bf(hn);                            \
                cdst[P * 132 + d] = cn;                                                \
            }                                                                          \
        }                                                                              \
    }                                                                                  \
} while (0)

    unsigned short* hs = H0;
    unsigned short* hd = H1;
    float* csrc = C1;   // unused at lvl 0
    float* cdst = C0;
    int parents = 32;

    #pragma unroll
    for (int lvl = 0; lvl < 4; ++lvl) {
        const bool last = (lvl == 3);
        const bool hiv = (parents > 16);
        f32x4 acc0[5], acc1[5];
        #pragma unroll
        for (int g = 0; g < 5; ++g) {
            acc0[g] = (f32x4){0.f, 0.f, 0.f, 0.f};
            acc1[g] = (f32x4){0.f, 0.f, 0.f, 0.f};
        }
        #pragma unroll
        for (int kc = 0; kc < 8; ++kc) {
            int q = (kc * 4 + kg) ^ (col & 7);
            short8 a0 = *(const short8*)&hs[col * 256 + q * 8];
            #pragma unroll
            for (int g = 0; g < 5; ++g)
                acc0[g] = __builtin_amdgcn_mfma_f32_16x16x32_bf16(a0, Breg[g][kc], acc0[g], 0, 0, 0);
            if (hiv) {
                short8 a1 = *(const short8*)&hs[(16 + col) * 256 + q * 8];
                #pragma unroll
                for (int g = 0; g < 5; ++g)
                    acc1[g] = __builtin_amdgcn_mfma_f32_16x16x32_bf16(a1, Breg[g][kc], acc1[g], 0, 0, 0);
            }
        }
        EPI(acc0, 0);
        if (hiv) EPI(acc1, 1);
        __syncthreads();
        { unsigned short* th = hs; hs = hd; hd = th; }
        { float* tc = csrc; csrc = cdst; cdst = tc; }
        parents >>= 1;
    }
#undef EPI

    if (LASTPASS) {
        if (t < 128) {
            out[t] = 0.25f * (ROOTS[t] + ROOTS[128 + t] + ROOTS[256 + t] + ROOTS[384 + t]);
        } else if (t < 256) {
            out[t] = 0.0f;
        }
    }
}

extern "C" void kernel_launch(void* const* d_in, const int* in_sizes, int n_in,
                              void* d_out, int out_size, void* d_ws, size_t ws_size,
                              hipStream_t stream) {
    const float* leaf = (const float*)d_in[0];
    const float* W_up = (const float*)d_in[1];
    const float* b_up = (const float*)d_in[2];
    float* out = (float*)d_out;
    char* ws = (char*)d_ws;

    unsigned short* Wb = (unsigned short*)ws;                  // 320 KB
    unsigned short* h1 = (unsigned short*)(ws + 0x100000);     // 16384x128 bf16 = 4 MB
    float* c1 = (float*)(ws + 0x500000);                       // 16384x128 f32 = 8 MB
    unsigned short* h2 = (unsigned short*)(ws + 0xD00000);     // 1024x128 bf16 = 256 KB
    float* c2 = (float*)(ws + 0xD40000);                       // 512 KB
    unsigned short* h3 = (unsigned short*)(ws + 0xDC0000);     // 64x128 bf16 = 16 KB
    float* c3 = (float*)(ws + 0xDC8000);                       // 32 KB

    convert_w_kernel<<<160, 256, 0, stream>>>(W_up, Wb);

    // P1: 262144 leaves -> 16384 rows (levels 1-4) + leaves write-through
    fused4_kernel<true, false><<<4096, 512, 0, stream>>>(leaf, nullptr, Wb, b_up, h1, c1, out);
    // P2: 16384 -> 1024 (levels 5-8)
    fused4_kernel<false, false><<<256, 512, 0, stream>>>(h1, c1, Wb, b_up, h2, c2, nullptr);
    // P3: 1024 -> 64 (levels 9-12)
    fused4_kernel<false, false><<<16, 512, 0, stream>>>(h2, c2, Wb, b_up, h3, c3, nullptr);
    // P4: 64 -> 4 roots (levels 13-16) + mean + out[128:256]=0
    fused4_kernel<false, true><<<1, 512, 0, stream>>>(h3, c3, Wb, b_up, nullptr, nullptr, out);
}